// Round 12
// baseline (290.241 us; speedup 1.0000x reference)
//
#include <hip/hip_runtime.h>
#include <hip/hip_bf16.h>

#define NN 100000   // nodes
#define FF 10       // input features
#define HH 20       // hidden dim
#define GG 512      // graphs
#define LL 2        // labels

#define NB 500      // dst buckets
#define BNODES 200  // nodes per bucket (NN / NB)
#define CAP 7168    // per-bucket capacity (mean 6400, sigma ~80 -> 9.6 sigma)
#define HB 100      // nodes per half-bucket (layer kernels)
#define SCAP 3712   // per-half-bucket edge capacity (mean 3200, ~9 sigma)
#define TILE 4096   // edges per block in multisplit
#define SRC_BITS 17
#define SRC_MASK 0x1FFFFu

// bf16 helpers (storage-only; all math in f32)
__device__ inline unsigned short f2bf(float f) {
  unsigned u = __float_as_uint(f);
  unsigned r = u + 0x7FFFu + ((u >> 16) & 1u);
  return (unsigned short)(r >> 16);
}
__device__ inline float bflo(unsigned u) { return __uint_as_float(u << 16); }
__device__ inline float bfhi(unsigned u) { return __uint_as_float(u & 0xFFFF0000u); }

// ---------------------------------------------------------------------------
// Cast x f32->bf16 (nt reads; x is touched once) and zero cursors/pool accums.
// ---------------------------------------------------------------------------
__global__ __launch_bounds__(256) void cast_init_kernel(
    const float* __restrict__ x, unsigned short* __restrict__ xb,
    float* __restrict__ sump, int* __restrict__ maxp, float* __restrict__ cnt,
    int* __restrict__ cursor, int n) {
  int i = blockIdx.x * 256 + threadIdx.x;
  if (i < n) xb[i] = f2bf(__builtin_nontemporal_load(x + i));
  if (i < GG * HH) {
    sump[i] = 0.0f;
    maxp[i] = 0;
  }
  if (i < GG) cnt[i] = 0.0f;
  if (i < NB) cursor[i] = 0;
}

// ---------------------------------------------------------------------------
// Multisplit (512 thr) with LDS-staged COALESCED writes into fixed-CAP bucket
// regions. Payload pack: (local_dst << 17) | src.
// ---------------------------------------------------------------------------
__global__ __launch_bounds__(512) void multisplit_kernel(
    const int* __restrict__ src, const int* __restrict__ dst,
    int* __restrict__ cursor, unsigned int* __restrict__ pay, int E) {
  __shared__ int lhist[NB];
  __shared__ int lofs[NB];
  __shared__ int gbase[NB];
  __shared__ int lcur[NB];
  __shared__ unsigned int sord[TILE];
  __shared__ unsigned short sdbk[TILE];
  __shared__ int ss[512];
  int t = threadIdx.x;
  if (t < NB) lhist[t] = 0;
  __syncthreads();

  int base = blockIdx.x * TILE;
  int count = E - base;
  if (count > TILE) count = TILE;

  for (int i = t; i < count; i += 512)
    atomicAdd(&lhist[dst[base + i] / BNODES], 1);
  __syncthreads();

  // exclusive scan of lhist (NB=500), 1 elem/thread
  int own = (t < NB) ? lhist[t] : 0;
  ss[t] = own;
  __syncthreads();
  for (int off = 1; off < 512; off <<= 1) {
    int a0 = (t >= off) ? ss[t - off] : 0;
    __syncthreads();
    ss[t] += a0;
    __syncthreads();
  }
  // reserve global ranges (clamped: >9-sigma overflow drops edges, no OOB)
  if (t < NB) {
    lofs[t] = ss[t] - own;
    int bo = own ? atomicAdd(&cursor[t], own) : 0;
    if (bo > CAP - own) bo = CAP - own;
    gbase[t] = t * CAP + bo;
    lcur[t] = 0;
  }
  __syncthreads();

  // pass 2: rank + scatter into bucket-grouped LDS order
  for (int i = t; i < count; i += 512) {
    int e = base + i;
    int d = __builtin_nontemporal_load(dst + e);
    int s = __builtin_nontemporal_load(src + e);
    int bk = d / BNODES;
    int ld = d - bk * BNODES;
    int r = atomicAdd(&lcur[bk], 1);
    int slot = lofs[bk] + r;
    sord[slot] = ((unsigned)ld << SRC_BITS) | (unsigned)s;
    sdbk[slot] = (unsigned short)bk;
  }
  __syncthreads();

  // coalesced run writes
  for (int i = t; i < count; i += 512) {
    int bk = sdbk[i];
    pay[gbase[bk] + (i - lofs[bk])] = sord[i];
  }
}

// ---------------------------------------------------------------------------
// Fused HALF-bucket layer (block b2 owns nodes [b2*100, b2*100+100)):
//  A) two NT passes over the owning bucket's pay run (stream hint -> the
//     14.3MB pay stream does not evict the 2-4MB h array from per-XCD L2;
//     that L2 residency is what the random gather reads depend on):
//     hist of own-half edges -> scan -> scatter src into LDS CSR
//  B) gather: task = (local node, chunk); VGPR accumulate; plain LDS store
//  C) dense + bias + root + ReLU from LDS -> bf16 hout
// ---------------------------------------------------------------------------
template<int DIN>
__global__ __launch_bounds__(512) void bucket_layer_kernel(
    const unsigned short* __restrict__ hin, const unsigned int* __restrict__ pay,
    const int* __restrict__ cursor, const float* __restrict__ Wrel,
    const float* __restrict__ bias, const float* __restrict__ Wroot,
    unsigned short* __restrict__ hout) {
  constexpr int AST = (DIN == 10) ? 11 : 21;  // padded acc stride
  constexpr int CH = DIN / 5;                 // features per chunk (2 or 4)
  __shared__ int sSrc[SCAP];
  __shared__ float acc[HB * AST];
  __shared__ unsigned short roots[HB * DIN];
  __shared__ float sWrel[DIN * HH];
  __shared__ float sWroot[DIN * HH];
  __shared__ float sb[HH];
  __shared__ int lhist[HB];
  __shared__ int lcur[HB];
  __shared__ int sRofs[HB];
  __shared__ int sRend[HB];
  __shared__ int ss[128];
  int b2 = blockIdx.x;
  int bucket = b2 >> 1;
  int lo = (b2 & 1) * HB;       // local node offset within bucket
  int t = threadIdx.x;
  int nbase = b2 * HB;          // global node base

  for (int i = t; i < DIN * HH; i += 512) {
    sWrel[i] = Wrel[i];
    sWroot[i] = Wroot[i];
  }
  if (t < HH) sb[t] = bias[t];
  if (t < HB) lhist[t] = 0;
  {
    const unsigned* rs = (const unsigned*)(hin + (size_t)nbase * DIN);
    unsigned* rd = (unsigned*)roots;
    for (int i = t; i < HB * DIN / 2; i += 512) rd[i] = rs[i];
  }
  __syncthreads();

  int ecnt = cursor[bucket];
  if (ecnt > CAP) ecnt = CAP;
  const unsigned int* mypay = pay + (size_t)bucket * CAP;

  // A1: histogram of own-half edges (nt stream)
  for (int i = t; i < ecnt; i += 512) {
    int ld = (int)(__builtin_nontemporal_load(mypay + i) >> SRC_BITS) - lo;
    if ((unsigned)ld < HB) atomicAdd(&lhist[ld], 1);
  }
  __syncthreads();

  // A2: scan (100 entries, first 128 threads)
  int own = (t < HB) ? lhist[t] : 0;
  if (t < 128) ss[t] = own;
  __syncthreads();
  for (int off = 1; off < 128; off <<= 1) {
    int a0 = (t < 128 && t >= off) ? ss[t - off] : 0;
    __syncthreads();
    if (t < 128) ss[t] += a0;
    __syncthreads();
  }
  if (t < HB) {
    int ex = ss[t] - own;
    sRofs[t] = ex;
    int en = ex + own;
    sRend[t] = en < SCAP ? en : SCAP;
    lcur[t] = 0;
  }
  __syncthreads();

  // A3: scatter src into node-sorted LDS order (nt stream)
  for (int i = t; i < ecnt; i += 512) {
    unsigned p = __builtin_nontemporal_load(mypay + i);
    int ld = (int)(p >> SRC_BITS) - lo;
    if ((unsigned)ld < HB) {
      int r = atomicAdd(&lcur[ld], 1);
      int slot = sRofs[ld] + r;
      if (slot < SCAP) sSrc[slot] = (int)(p & SRC_MASK);
    }
  }
  __syncthreads();

  // B: gather with register accumulation (task = node x chunk)
  if (t < HB * 5) {
    int ln = t / 5;
    int c = t - ln * 5;
    int k0 = sRofs[ln], k1 = sRend[ln];
    float a0 = 0, a1 = 0, a2 = 0, a3 = 0;
    const unsigned short* xb = hin + c * CH;
    if (CH == 4) {
      for (int k = k0; k < k1; k++) {
        uint2 u = *(const uint2*)(xb + (size_t)sSrc[k] * DIN);
        a0 += bflo(u.x);
        a1 += bfhi(u.x);
        a2 += bflo(u.y);
        a3 += bfhi(u.y);
      }
    } else {
      for (int k = k0; k < k1; k++) {
        unsigned u = *(const unsigned*)(xb + (size_t)sSrc[k] * DIN);
        a0 += bflo(u);
        a1 += bfhi(u);
      }
    }
    float* a = acc + ln * AST + c * CH;
    if (CH == 4) {
      a[0] = a0; a[1] = a1; a[2] = a2; a[3] = a3;
    } else {
      a[0] = a0; a[1] = a1;
    }
  }
  __syncthreads();

  // C: dense + bias + root + relu -> global bf16
  for (int idx = t; idx < HB * HH; idx += 512) {
    int ln = idx / HH;
    int j = idx - ln * HH;
    const float* a = acc + ln * AST;
    const unsigned short* r = roots + ln * DIN;
    float v = sb[j];
#pragma unroll
    for (int f = 0; f < DIN; f++) {
      v += a[f] * sWrel[f * HH + j];
      v += bflo((unsigned)r[f]) * sWroot[f * HH + j];
    }
    hout[(size_t)nbase * HH + idx] = f2bf(fmaxf(v, 0.0f));
  }
}

// ---------------------------------------------------------------------------
// Layer 3 + pooling (half-bucket): dense staged in registers then written
// over acc (dead), then block-local pool + few global atomics.
// Post-ReLU >= 0 -> int atomicMax on float bits order-correct; zero init
// reproduces where(cnt>0, max, 0).
// ---------------------------------------------------------------------------
__global__ __launch_bounds__(512) void bucket_layer_pool_kernel(
    const unsigned short* __restrict__ hin, const unsigned int* __restrict__ pay,
    const int* __restrict__ cursor, const float* __restrict__ Wrel,
    const float* __restrict__ bias, const float* __restrict__ Wroot,
    const int* __restrict__ batch, float* __restrict__ sump,
    int* __restrict__ maxp, float* __restrict__ cnt) {
  constexpr int DIN = 20;
  constexpr int AST = 21;
  __shared__ int sSrc[SCAP];
  __shared__ float acc[HB * AST];
  __shared__ unsigned short roots[HB * DIN];
  __shared__ int sBatch[HB];
  __shared__ float sWrel[DIN * HH];
  __shared__ float sWroot[DIN * HH];
  __shared__ float sb[HH];
  __shared__ int lhist[HB];
  __shared__ int lcur[HB];
  __shared__ int sRofs[HB];
  __shared__ int sRend[HB];
  __shared__ int ss[128];
  int b2 = blockIdx.x;
  int bucket = b2 >> 1;
  int lo = (b2 & 1) * HB;
  int t = threadIdx.x;
  int nbase = b2 * HB;

  for (int i = t; i < DIN * HH; i += 512) {
    sWrel[i] = Wrel[i];
    sWroot[i] = Wroot[i];
  }
  if (t < HH) sb[t] = bias[t];
  if (t < HB) {
    lhist[t] = 0;
    sBatch[t] = batch[nbase + t];
  }
  {
    const unsigned* rs = (const unsigned*)(hin + (size_t)nbase * DIN);
    unsigned* rd = (unsigned*)roots;
    for (int i = t; i < HB * DIN / 2; i += 512) rd[i] = rs[i];
  }
  __syncthreads();

  int ecnt = cursor[bucket];
  if (ecnt > CAP) ecnt = CAP;
  const unsigned int* mypay = pay + (size_t)bucket * CAP;

  for (int i = t; i < ecnt; i += 512) {
    int ld = (int)(__builtin_nontemporal_load(mypay + i) >> SRC_BITS) - lo;
    if ((unsigned)ld < HB) atomicAdd(&lhist[ld], 1);
  }
  __syncthreads();

  int own = (t < HB) ? lhist[t] : 0;
  if (t < 128) ss[t] = own;
  __syncthreads();
  for (int off = 1; off < 128; off <<= 1) {
    int a0 = (t < 128 && t >= off) ? ss[t - off] : 0;
    __syncthreads();
    if (t < 128) ss[t] += a0;
    __syncthreads();
  }
  if (t < HB) {
    int ex = ss[t] - own;
    sRofs[t] = ex;
    int en = ex + own;
    sRend[t] = en < SCAP ? en : SCAP;
    lcur[t] = 0;
  }
  __syncthreads();

  for (int i = t; i < ecnt; i += 512) {
    unsigned p = __builtin_nontemporal_load(mypay + i);
    int ld = (int)(p >> SRC_BITS) - lo;
    if ((unsigned)ld < HB) {
      int r = atomicAdd(&lcur[ld], 1);
      int slot = sRofs[ld] + r;
      if (slot < SCAP) sSrc[slot] = (int)(p & SRC_MASK);
    }
  }
  __syncthreads();

  if (t < HB * 5) {
    int ln = t / 5;
    int c = t - ln * 5;
    int k0 = sRofs[ln], k1 = sRend[ln];
    float a0 = 0, a1 = 0, a2 = 0, a3 = 0;
    const unsigned short* xb = hin + c * 4;
    for (int k = k0; k < k1; k++) {
      uint2 u = *(const uint2*)(xb + (size_t)sSrc[k] * 20);
      a0 += bflo(u.x);
      a1 += bfhi(u.x);
      a2 += bflo(u.y);
      a3 += bfhi(u.y);
    }
    float* a = acc + ln * AST + c * 4;
    a[0] = a0; a[1] = a1; a[2] = a2; a[3] = a3;
  }
  __syncthreads();

  // dense into registers (acc is still being read), then overwrite acc
  float vreg[4];
#pragma unroll
  for (int u = 0; u < 4; u++) {
    int idx = t + u * 512;
    if (idx < HB * HH) {
      int ln = idx / HH;
      int j = idx - ln * HH;
      const float* a = acc + ln * AST;
      const unsigned short* r = roots + ln * DIN;
      float v = sb[j];
#pragma unroll
      for (int f = 0; f < DIN; f++) {
        v += a[f] * sWrel[f * HH + j];
        v += bflo((unsigned)r[f]) * sWroot[f * HH + j];
      }
      vreg[u] = fmaxf(v, 0.0f);
    }
  }
  __syncthreads();
#pragma unroll
  for (int u = 0; u < 4; u++) {
    int idx = t + u * 512;
    if (idx < HB * HH) {
      int ln = idx / HH;
      int j = idx - ln * HH;
      acc[ln * AST + j] = vreg[u];
    }
  }
  __syncthreads();

  // block-local pool over the graphs this half-bucket spans
  int g0 = sBatch[0];
  int g1 = sBatch[HB - 1];
  int ngr = g1 - g0 + 1;
  for (int it = t; it < ngr * HH; it += 512) {
    int gi = it / HH;
    int j = it - gi * HH;
    int g = g0 + gi;
    float s = 0.0f, m = 0.0f;
    int c = 0;
    for (int ln = 0; ln < HB; ln++) {
      if (sBatch[ln] == g) {
        float v = acc[ln * AST + j];
        s += v;
        m = fmaxf(m, v);
        c++;
      }
    }
    if (c) {
      atomicAdd(&sump[g * HH + j], s);
      atomicMax(&maxp[g * HH + j], __float_as_int(m));
      if (j == 0) atomicAdd(&cnt[g], (float)c);
    }
  }
}

__global__ __launch_bounds__(256) void readout_kernel(
    const float* __restrict__ sump, const int* __restrict__ maxp,
    const float* __restrict__ cnt, const float* __restrict__ Wlin,
    const float* __restrict__ blin, float* __restrict__ out) {
  int idx = blockIdx.x * 256 + threadIdx.x;
  if (idx >= GG * LL) return;
  int g = idx / LL;
  int l = idx - g * LL;
  float c = cnt[g];
  float inv = 1.0f / fmaxf(c, 1.0f);
  float acc = blin[l];
#pragma unroll
  for (int j = 0; j < HH; j++) {
    float mx = __int_as_float(maxp[g * HH + j]);
    float mean = sump[g * HH + j] * inv;
    acc += mx * Wlin[j * LL + l];
    acc += mean * Wlin[(HH + j) * LL + l];
  }
  out[idx] = acc;
}

extern "C" void kernel_launch(void* const* d_in, const int* in_sizes, int n_in,
                              void* d_out, int out_size, void* d_ws,
                              size_t ws_size, hipStream_t stream) {
  const float* x = (const float*)d_in[0];
  const int* edge_index = (const int*)d_in[1];
  const int* batch = (const int*)d_in[2];
  const float* W_rel1 = (const float*)d_in[3];
  const float* b1 = (const float*)d_in[4];
  const float* W_root1 = (const float*)d_in[5];
  const float* W_rel2 = (const float*)d_in[6];
  const float* b2 = (const float*)d_in[7];
  const float* W_root2 = (const float*)d_in[8];
  const float* W_rel3 = (const float*)d_in[9];
  const float* b3 = (const float*)d_in[10];
  const float* W_root3 = (const float*)d_in[11];
  const float* W_lin = (const float*)d_in[12];
  const float* b_lin = (const float*)d_in[13];
  float* out = (float*)d_out;

  const int E = in_sizes[1] / 2;
  const int n_nodes = in_sizes[0] / FF;  // == NN
  const int* src = edge_index;
  const int* dst = edge_index + E;

  // Workspace layout (chunks 16B aligned). cursor..cnt contiguous.
  unsigned int* pay = (unsigned int*)d_ws;       // NB*CAP u32 (14.3MB)
  int* cursor = (int*)(pay + (size_t)NB * CAP);  // 512
  float* sump = (float*)(cursor + 512);          // GG*HH
  int* maxp = (int*)(sump + GG * HH);            // GG*HH
  float* cnt = (float*)(maxp + GG * HH);         // 512
  unsigned short* xb = (unsigned short*)(cnt + 512);  // NN*FF bf16 (2MB)
  unsigned short* h1 = xb + (size_t)NN * FF;     // NN*HH bf16 (4MB)
  unsigned short* h2 = h1 + (size_t)NN * HH;     // NN*HH bf16 (4MB)

  const int edge_tiles = (E + TILE - 1) / TILE;

  // ---- Cast x to bf16 + zero cursors/pool accumulators ----
  cast_init_kernel<<<(n_nodes * FF + 255) / 256, 256, 0, stream>>>(
      x, xb, sump, maxp, cnt, cursor, n_nodes * FF);

  // ---- Edge partition: staged multisplit into fixed bucket regions ----
  multisplit_kernel<<<edge_tiles, 512, 0, stream>>>(src, dst, cursor, pay, E);

  // ---- Fused per-half-bucket layers (register-accumulated, nt pay) ----
  bucket_layer_kernel<FF><<<NB * 2, 512, 0, stream>>>(
      xb, pay, cursor, W_rel1, b1, W_root1, h1);
  bucket_layer_kernel<HH><<<NB * 2, 512, 0, stream>>>(
      h1, pay, cursor, W_rel2, b2, W_root2, h2);
  bucket_layer_pool_kernel<<<NB * 2, 512, 0, stream>>>(
      h2, pay, cursor, W_rel3, b3, W_root3, batch, sump, maxp, cnt);

  // ---- Readout ----
  readout_kernel<<<(GG * LL + 255) / 256, 256, 0, stream>>>(
      sump, maxp, cnt, W_lin, b_lin, out);
}

// Round 14
// 261.559 us; speedup vs baseline: 1.1097x; 1.1097x over previous
//
#include <hip/hip_runtime.h>
#include <hip/hip_bf16.h>

#define NN 100000   // nodes
#define FF 10       // input features
#define HH 20       // hidden dim
#define GG 512      // graphs
#define LL 2        // labels

#define NB 500      // dst buckets
#define BNODES 200  // nodes per bucket (NN / NB)
#define CAP 7168    // per-bucket capacity (mean 6400, ~9.6 sigma)
#define HB 100      // nodes per half-bucket (one layer block)
#define SCAP 3712   // per-half-bucket edge capacity (mean 3200, ~9 sigma)
#define TILE 4096   // edges per block in multisplit
#define SRC_BITS 17
#define SRC_MASK 0x1FFFFu

// bf16 helpers (storage-only; all math in f32)
__device__ inline unsigned short f2bf(float f) {
  unsigned u = __float_as_uint(f);
  unsigned r = u + 0x7FFFu + ((u >> 16) & 1u);
  return (unsigned short)(r >> 16);
}
__device__ inline float bflo(unsigned u) { return __uint_as_float(u << 16); }
__device__ inline float bfhi(unsigned u) { return __uint_as_float(u & 0xFFFF0000u); }

// ---------------------------------------------------------------------------
// Cast x f32->bf16 (nt reads; x touched once) and zero cursors/pool accums.
// ---------------------------------------------------------------------------
__global__ __launch_bounds__(256) void cast_init_kernel(
    const float* __restrict__ x, unsigned short* __restrict__ xb,
    float* __restrict__ sump, int* __restrict__ maxp, float* __restrict__ cnt,
    int* __restrict__ cursor, int n) {
  int i = blockIdx.x * 256 + threadIdx.x;
  if (i < n) xb[i] = f2bf(__builtin_nontemporal_load(x + i));
  if (i < GG * HH) {
    sump[i] = 0.0f;
    maxp[i] = 0;
  }
  if (i < GG) cnt[i] = 0.0f;
  if (i < NB) cursor[i] = 0;
}

// ---------------------------------------------------------------------------
// Multisplit (512 thr) with LDS-staged COALESCED writes into fixed-CAP bucket
// regions. Payload pack: (local_dst << 17) | src.
// ---------------------------------------------------------------------------
__global__ __launch_bounds__(512) void multisplit_kernel(
    const int* __restrict__ src, const int* __restrict__ dst,
    int* __restrict__ cursor, unsigned int* __restrict__ pay, int E) {
  __shared__ int lhist[NB];
  __shared__ int lofs[NB];
  __shared__ int gbase[NB];
  __shared__ int lcur[NB];
  __shared__ unsigned int sord[TILE];
  __shared__ unsigned short sdbk[TILE];
  __shared__ int ss[512];
  int t = threadIdx.x;
  if (t < NB) lhist[t] = 0;
  __syncthreads();

  int base = blockIdx.x * TILE;
  int count = E - base;
  if (count > TILE) count = TILE;

  for (int i = t; i < count; i += 512)
    atomicAdd(&lhist[dst[base + i] / BNODES], 1);
  __syncthreads();

  // exclusive scan of lhist (NB=500), 1 elem/thread
  int own = (t < NB) ? lhist[t] : 0;
  ss[t] = own;
  __syncthreads();
  for (int off = 1; off < 512; off <<= 1) {
    int a0 = (t >= off) ? ss[t - off] : 0;
    __syncthreads();
    ss[t] += a0;
    __syncthreads();
  }
  // reserve global ranges (clamped: >9-sigma overflow drops edges, no OOB)
  if (t < NB) {
    lofs[t] = ss[t] - own;
    int bo = own ? atomicAdd(&cursor[t], own) : 0;
    if (bo > CAP - own) bo = CAP - own;
    gbase[t] = t * CAP + bo;
    lcur[t] = 0;
  }
  __syncthreads();

  // pass 2: rank + scatter into bucket-grouped LDS order
  for (int i = t; i < count; i += 512) {
    int e = base + i;
    int d = __builtin_nontemporal_load(dst + e);
    int s = __builtin_nontemporal_load(src + e);
    int bk = d / BNODES;
    int ld = d - bk * BNODES;
    int r = atomicAdd(&lcur[bk], 1);
    int slot = lofs[bk] + r;
    sord[slot] = ((unsigned)ld << SRC_BITS) | (unsigned)s;
    sdbk[slot] = (unsigned short)bk;
  }
  __syncthreads();

  // coalesced run writes
  for (int i = t; i < count; i += 512) {
    int bk = sdbk[i];
    pay[gbase[bk] + (i - lofs[bk])] = sord[i];
  }
}

// ---------------------------------------------------------------------------
// One-time CSR finalize: per bucket, sort pay run by local node into global
// srt (same fixed-CAP region, so each half-bucket's segment is contiguous),
// and write absolute rofs/rend per node. Writes confined to own region.
// ---------------------------------------------------------------------------
__global__ __launch_bounds__(256) void bucket_csr_kernel(
    const unsigned int* __restrict__ pay, const int* __restrict__ cursor,
    int* __restrict__ srt, int* __restrict__ rofs, int* __restrict__ rend) {
  __shared__ int lhist[BNODES];
  __shared__ int lofs[BNODES];
  __shared__ int lcur[BNODES];
  __shared__ int ss[256];
  int b = blockIdx.x;
  int t = threadIdx.x;
  int k0 = b * CAP;
  int ecnt = cursor[b];
  if (ecnt > CAP) ecnt = CAP;

  if (t < BNODES) lhist[t] = 0;
  __syncthreads();
  for (int k = t; k < ecnt; k += 256)
    atomicAdd(&lhist[pay[k0 + k] >> SRC_BITS], 1);
  __syncthreads();

  int own = (t < BNODES) ? lhist[t] : 0;
  ss[t] = own;
  __syncthreads();
  for (int off = 1; off < 256; off <<= 1) {
    int a0 = (t >= off) ? ss[t - off] : 0;
    __syncthreads();
    ss[t] += a0;
    __syncthreads();
  }
  if (t < BNODES) {
    int ex = ss[t] - own;
    lofs[t] = ex;
    lcur[t] = 0;
    rofs[b * BNODES + t] = k0 + ex;
    rend[b * BNODES + t] = k0 + ex + own;
  }
  __syncthreads();

  for (int k = t; k < ecnt; k += 256) {
    unsigned p = pay[k0 + k];
    int ld = p >> SRC_BITS;
    int r = atomicAdd(&lcur[ld], 1);
    srt[k0 + lofs[ld] + r] = (int)(p & SRC_MASK);
  }
}

// ---------------------------------------------------------------------------
// Fused HALF-bucket layer (block b2 owns nodes [b2*100, b2*100+100)):
//  A) stage weights/roots + coalesced COPY of the contiguous srt segment
//     into LDS (no hist/scan/LDS-atomics — CSR was built once globally)
//  B) gather: task = (node, chunk); 5 consecutive threads share a node;
//     VGPR accumulate; plain LDS store into padded acc
//  C) dense + bias + root + ReLU from LDS -> bf16 hout
// ---------------------------------------------------------------------------
template<int DIN>
__global__ __launch_bounds__(512) void bucket_layer_kernel(
    const unsigned short* __restrict__ hin, const int* __restrict__ srt,
    const int* __restrict__ rofs, const int* __restrict__ rend,
    const float* __restrict__ Wrel, const float* __restrict__ bias,
    const float* __restrict__ Wroot, unsigned short* __restrict__ hout) {
  constexpr int AST = (DIN == 10) ? 11 : 21;
  constexpr int CH = DIN / 5;
  __shared__ int sSrc[SCAP];
  __shared__ float acc[HB * AST];
  __shared__ unsigned short roots[HB * DIN];
  __shared__ float sWrel[DIN * HH];
  __shared__ float sWroot[DIN * HH];
  __shared__ float sb[HH];
  __shared__ int sRofs[HB];
  __shared__ int sRend[HB];
  __shared__ int sSeg0, sSegLen;
  int b2 = blockIdx.x;
  int t = threadIdx.x;
  int nbase = b2 * HB;

  for (int i = t; i < DIN * HH; i += 512) {
    sWrel[i] = Wrel[i];
    sWroot[i] = Wroot[i];
  }
  if (t < HH) sb[t] = bias[t];
  if (t < HB) {
    sRofs[t] = rofs[nbase + t];
    sRend[t] = rend[nbase + t];
  }
  if (t == 0) {
    int s0 = rofs[nbase];
    int sl = rend[nbase + HB - 1] - s0;
    sSeg0 = s0;
    sSegLen = sl < SCAP ? sl : SCAP;
  }
  {
    const unsigned* rs = (const unsigned*)(hin + (size_t)nbase * DIN);
    unsigned* rd = (unsigned*)roots;
    for (int i = t; i < HB * DIN / 2; i += 512) rd[i] = rs[i];
  }
  __syncthreads();

  int seg0 = sSeg0, seglen = sSegLen;
  for (int i = t; i < seglen; i += 512) sSrc[i] = srt[seg0 + i];
  __syncthreads();

  if (t < HB * 5) {
    int ln = t / 5;
    int c = t - ln * 5;
    int k0 = sRofs[ln] - seg0;
    int k1 = sRend[ln] - seg0;
    if (k1 > seglen) k1 = seglen;  // >9-sigma clamp, never in practice
    float a0 = 0, a1 = 0, a2 = 0, a3 = 0;
    const unsigned short* xb = hin + c * CH;
    if (CH == 4) {
      for (int k = k0; k < k1; k++) {
        uint2 u = *(const uint2*)(xb + (size_t)sSrc[k] * DIN);
        a0 += bflo(u.x);
        a1 += bfhi(u.x);
        a2 += bflo(u.y);
        a3 += bfhi(u.y);
      }
    } else {
      for (int k = k0; k < k1; k++) {
        unsigned u = *(const unsigned*)(xb + (size_t)sSrc[k] * DIN);
        a0 += bflo(u);
        a1 += bfhi(u);
      }
    }
    float* a = acc + ln * AST + c * CH;
    if (CH == 4) {
      a[0] = a0; a[1] = a1; a[2] = a2; a[3] = a3;
    } else {
      a[0] = a0; a[1] = a1;
    }
  }
  __syncthreads();

  for (int idx = t; idx < HB * HH; idx += 512) {
    int ln = idx / HH;
    int j = idx - ln * HH;
    const float* a = acc + ln * AST;
    const unsigned short* r = roots + ln * DIN;
    float v = sb[j];
#pragma unroll
    for (int f = 0; f < DIN; f++) {
      v += a[f] * sWrel[f * HH + j];
      v += bflo((unsigned)r[f]) * sWroot[f * HH + j];
    }
    hout[(size_t)nbase * HH + idx] = f2bf(fmaxf(v, 0.0f));
  }
}

// ---------------------------------------------------------------------------
// Layer 3 + pooling (half-bucket): same staging; dense into registers then
// written over acc (dead), then block-local pool + few global atomics.
// Post-ReLU >= 0 -> int atomicMax on float bits order-correct; zero init
// reproduces where(cnt>0, max, 0).
// ---------------------------------------------------------------------------
__global__ __launch_bounds__(512) void bucket_layer_pool_kernel(
    const unsigned short* __restrict__ hin, const int* __restrict__ srt,
    const int* __restrict__ rofs, const int* __restrict__ rend,
    const float* __restrict__ Wrel, const float* __restrict__ bias,
    const float* __restrict__ Wroot, const int* __restrict__ batch,
    float* __restrict__ sump, int* __restrict__ maxp,
    float* __restrict__ cnt) {
  constexpr int DIN = 20;
  constexpr int AST = 21;
  __shared__ int sSrc[SCAP];
  __shared__ float acc[HB * AST];
  __shared__ unsigned short roots[HB * DIN];
  __shared__ int sBatch[HB];
  __shared__ float sWrel[DIN * HH];
  __shared__ float sWroot[DIN * HH];
  __shared__ float sb[HH];
  __shared__ int sRofs[HB];
  __shared__ int sRend[HB];
  __shared__ int sSeg0, sSegLen;
  int b2 = blockIdx.x;
  int t = threadIdx.x;
  int nbase = b2 * HB;

  for (int i = t; i < DIN * HH; i += 512) {
    sWrel[i] = Wrel[i];
    sWroot[i] = Wroot[i];
  }
  if (t < HH) sb[t] = bias[t];
  if (t < HB) {
    sRofs[t] = rofs[nbase + t];
    sRend[t] = rend[nbase + t];
    sBatch[t] = batch[nbase + t];
  }
  if (t == 0) {
    int s0 = rofs[nbase];
    int sl = rend[nbase + HB - 1] - s0;
    sSeg0 = s0;
    sSegLen = sl < SCAP ? sl : SCAP;
  }
  {
    const unsigned* rs = (const unsigned*)(hin + (size_t)nbase * DIN);
    unsigned* rd = (unsigned*)roots;
    for (int i = t; i < HB * DIN / 2; i += 512) rd[i] = rs[i];
  }
  __syncthreads();

  int seg0 = sSeg0, seglen = sSegLen;
  for (int i = t; i < seglen; i += 512) sSrc[i] = srt[seg0 + i];
  __syncthreads();

  if (t < HB * 5) {
    int ln = t / 5;
    int c = t - ln * 5;
    int k0 = sRofs[ln] - seg0;
    int k1 = sRend[ln] - seg0;
    if (k1 > seglen) k1 = seglen;
    float a0 = 0, a1 = 0, a2 = 0, a3 = 0;
    const unsigned short* xb = hin + c * 4;
    for (int k = k0; k < k1; k++) {
      uint2 u = *(const uint2*)(xb + (size_t)sSrc[k] * 20);
      a0 += bflo(u.x);
      a1 += bfhi(u.x);
      a2 += bflo(u.y);
      a3 += bfhi(u.y);
    }
    float* a = acc + ln * AST + c * 4;
    a[0] = a0; a[1] = a1; a[2] = a2; a[3] = a3;
  }
  __syncthreads();

  float vreg[4];
#pragma unroll
  for (int u = 0; u < 4; u++) {
    int idx = t + u * 512;
    if (idx < HB * HH) {
      int ln = idx / HH;
      int j = idx - ln * HH;
      const float* a = acc + ln * AST;
      const unsigned short* r = roots + ln * DIN;
      float v = sb[j];
#pragma unroll
      for (int f = 0; f < DIN; f++) {
        v += a[f] * sWrel[f * HH + j];
        v += bflo((unsigned)r[f]) * sWroot[f * HH + j];
      }
      vreg[u] = fmaxf(v, 0.0f);
    }
  }
  __syncthreads();
#pragma unroll
  for (int u = 0; u < 4; u++) {
    int idx = t + u * 512;
    if (idx < HB * HH) {
      int ln = idx / HH;
      int j = idx - ln * HH;
      acc[ln * AST + j] = vreg[u];
    }
  }
  __syncthreads();

  int g0 = sBatch[0];
  int g1 = sBatch[HB - 1];
  int ngr = g1 - g0 + 1;
  for (int it = t; it < ngr * HH; it += 512) {
    int gi = it / HH;
    int j = it - gi * HH;
    int g = g0 + gi;
    float s = 0.0f, m = 0.0f;
    int c = 0;
    for (int ln = 0; ln < HB; ln++) {
      if (sBatch[ln] == g) {
        float v = acc[ln * AST + j];
        s += v;
        m = fmaxf(m, v);
        c++;
      }
    }
    if (c) {
      atomicAdd(&sump[g * HH + j], s);
      atomicMax(&maxp[g * HH + j], __float_as_int(m));
      if (j == 0) atomicAdd(&cnt[g], (float)c);
    }
  }
}

__global__ __launch_bounds__(256) void readout_kernel(
    const float* __restrict__ sump, const int* __restrict__ maxp,
    const float* __restrict__ cnt, const float* __restrict__ Wlin,
    const float* __restrict__ blin, float* __restrict__ out) {
  int idx = blockIdx.x * 256 + threadIdx.x;
  if (idx >= GG * LL) return;
  int g = idx / LL;
  int l = idx - g * LL;
  float c = cnt[g];
  float inv = 1.0f / fmaxf(c, 1.0f);
  float acc = blin[l];
#pragma unroll
  for (int j = 0; j < HH; j++) {
    float mx = __int_as_float(maxp[g * HH + j]);
    float mean = sump[g * HH + j] * inv;
    acc += mx * Wlin[j * LL + l];
    acc += mean * Wlin[(HH + j) * LL + l];
  }
  out[idx] = acc;
}

extern "C" void kernel_launch(void* const* d_in, const int* in_sizes, int n_in,
                              void* d_out, int out_size, void* d_ws,
                              size_t ws_size, hipStream_t stream) {
  const float* x = (const float*)d_in[0];
  const int* edge_index = (const int*)d_in[1];
  const int* batch = (const int*)d_in[2];
  const float* W_rel1 = (const float*)d_in[3];
  const float* b1 = (const float*)d_in[4];
  const float* W_root1 = (const float*)d_in[5];
  const float* W_rel2 = (const float*)d_in[6];
  const float* b2 = (const float*)d_in[7];
  const float* W_root2 = (const float*)d_in[8];
  const float* W_rel3 = (const float*)d_in[9];
  const float* b3 = (const float*)d_in[10];
  const float* W_root3 = (const float*)d_in[11];
  const float* W_lin = (const float*)d_in[12];
  const float* b_lin = (const float*)d_in[13];
  float* out = (float*)d_out;

  const int E = in_sizes[1] / 2;
  const int n_nodes = in_sizes[0] / FF;  // == NN
  const int* src = edge_index;
  const int* dst = edge_index + E;

  // Workspace layout (16B-aligned chunks)
  unsigned int* pay = (unsigned int*)d_ws;       // NB*CAP u32 (14.3MB)
  int* srt = (int*)(pay + (size_t)NB * CAP);     // NB*CAP (14.3MB)
  int* rofs = srt + (size_t)NB * CAP;            // NN
  int* rend = rofs + NN;                         // NN
  int* cursor = rend + NN;                       // 512
  float* sump = (float*)(cursor + 512);          // GG*HH
  int* maxp = (int*)(sump + GG * HH);            // GG*HH
  float* cnt = (float*)(maxp + GG * HH);         // 512
  unsigned short* xb = (unsigned short*)(cnt + 512);  // NN*FF bf16 (2MB)
  unsigned short* h1 = xb + (size_t)NN * FF;     // NN*HH bf16 (4MB)
  unsigned short* h2 = h1 + (size_t)NN * HH;     // NN*HH bf16 (4MB)

  const int edge_tiles = (E + TILE - 1) / TILE;

  // ---- Cast x to bf16 + zero cursors/pool accumulators ----
  cast_init_kernel<<<(n_nodes * FF + 255) / 256, 256, 0, stream>>>(
      x, xb, sump, maxp, cnt, cursor, n_nodes * FF);

  // ---- Edge partition + one-time CSR build ----
  multisplit_kernel<<<edge_tiles, 512, 0, stream>>>(src, dst, cursor, pay, E);
  bucket_csr_kernel<<<NB, 256, 0, stream>>>(pay, cursor, srt, rofs, rend);

  // ---- Fused per-half-bucket layers (global CSR, LDS-copied segment) ----
  bucket_layer_kernel<FF><<<NB * 2, 512, 0, stream>>>(
      xb, srt, rofs, rend, W_rel1, b1, W_root1, h1);
  bucket_layer_kernel<HH><<<NB * 2, 512, 0, stream>>>(
      h1, srt, rofs, rend, W_rel2, b2, W_root2, h2);
  bucket_layer_pool_kernel<<<NB * 2, 512, 0, stream>>>(
      h2, srt, rofs, rend, W_rel3, b3, W_root3, batch, sump, maxp, cnt);

  // ---- Readout ----
  readout_kernel<<<(GG * LL + 255) / 256, 256, 0, stream>>>(
      sump, maxp, cnt, W_lin, b_lin, out);
}